// Round 1
// baseline (3228.416 us; speedup 1.0000x reference)
//
#include <hip/hip_runtime.h>
#include <hip/hip_bf16.h>

// GRU forward, persistent-scan design:
//   - 16 workgroups (one per 16 batch rows), 512 threads (8 waves).
//   - Each wave owns 32 hidden columns; h kept in fp32 registers (8/lane).
//   - Per step: phase A computes r,z = sigmoid([h|x]@[H|W] + b) via MFMA,
//     writes r*h (f16) to LDS; barrier; phase B computes g = tanh([rh|x]@[Hg|Wg]+bg),
//     blends h_new, writes out + LDS f16 h for next step's A-operand; barrier.
//   - B-operands pre-fragmented to MFMA lane layout in workspace (480 KB, L2-hot).
//   - LDS A-tiles XOR-swizzled (byte ^= (row&7)<<4) to kill bank conflicts.

typedef _Float16 f16;
typedef _Float16 half8 __attribute__((ext_vector_type(8)));
typedef float floatx4 __attribute__((ext_vector_type(4)));

#define MFMA16(a, b, c) __builtin_amdgcn_mfma_f32_16x16x32_f16((a), (b), (c), 0, 0, 0)

// ---------------- prep: build fragmented B-operand tables ----------------
// Layout: Bfrag[gate 3][nt 16][kt 10][lane 64][8 f16]
//   col = nt*16 + (lane&15);  k = kt*32 + (lane>>4)*8 + i
//   k < 256 -> H_g[k][col];  k >= 256 -> W_g[k-256][col]
__global__ void gru_prep(const float* __restrict__ Wr, const float* __restrict__ Wz,
                         const float* __restrict__ Wg, const float* __restrict__ Hr,
                         const float* __restrict__ Hz, const float* __restrict__ Hg,
                         f16* __restrict__ B) {
    int idx = blockIdx.x * 256 + threadIdx.x;   // 0 .. 30719 == 3*16*10*64-1
    int lane = idx & 63;
    int rest = idx >> 6;
    int kt = rest % 10;
    rest /= 10;
    int nt = rest & 15;
    int g  = rest >> 4;
    if (g >= 3) return;
    const float* H = (g == 0) ? Hr : (g == 1) ? Hz : Hg;
    const float* W = (g == 0) ? Wr : (g == 1) ? Wz : Wg;
    int col   = nt * 16 + (lane & 15);
    int kbase = kt * 32 + (lane >> 4) * 8;
    half8 v;
#pragma unroll
    for (int i = 0; i < 8; ++i) {
        int k = kbase + i;
        float val = (k < 256) ? H[k * 256 + col] : W[(k - 256) * 256 + col];
        v[i] = (f16)val;
    }
    *(half8*)(B + (size_t)idx * 8) = v;
}

// ---------------- persistent scan kernel ----------------
__global__ void __launch_bounds__(512, 1)
gru_scan(const float* __restrict__ x,
         const float* __restrict__ br, const float* __restrict__ bz,
         const float* __restrict__ bg,
         const f16* __restrict__ Bfrag,
         float* __restrict__ out) {
    __shared__ __align__(16) unsigned char sH[8192];     // h f16 [16][256], swizzled
    __shared__ __align__(16) unsigned char sRH[8192];    // r*h f16 [16][256], swizzled
    __shared__ __align__(16) unsigned char sX[2][2048];  // x_t f16 [16][64], swizzled, dbuf

    const int tid  = threadIdx.x;
    const int wave = tid >> 6;        // 0..7
    const int lane = tid & 63;
    const int cl   = lane & 15;       // MFMA col (B/D) and A-row index
    const int rq   = lane >> 4;       // 0..3
    const int b0   = blockIdx.x * 16; // batch row block
    const int nt0  = wave * 2, nt1 = wave * 2 + 1;
    const int col0 = nt0 * 16 + cl, col1 = nt1 * 16 + cl;

    // A-fragment addressing: row = cl, k = kt*32 + rq*8 (+i)
    const int abase = cl * 512;            // row stride 512 B in sH/sRH
    const int asw   = (cl & 7) << 4;       // XOR swizzle for this A-row

    const float bR0 = br[col0], bR1 = br[col1];
    const float bZ0 = bz[col0], bZ1 = bz[col1];
    const float bG0 = bg[col0], bG1 = bg[col1];

    const half8* Bb  = (const half8*)Bfrag;   // one half8 per [.,.,.,lane]
    const half8* pR0 = Bb + (size_t)((0 * 16 + nt0) * 10) * 64 + lane;
    const half8* pR1 = Bb + (size_t)((0 * 16 + nt1) * 10) * 64 + lane;
    const half8* pZ0 = Bb + (size_t)((1 * 16 + nt0) * 10) * 64 + lane;
    const half8* pZ1 = Bb + (size_t)((1 * 16 + nt1) * 10) * 64 + lane;
    const half8* pG0 = Bb + (size_t)((2 * 16 + nt0) * 10) * 64 + lane;
    const half8* pG1 = Bb + (size_t)((2 * 16 + nt1) * 10) * 64 + lane;

    float h0_[4] = {0.f, 0.f, 0.f, 0.f};   // fp32 master h, rows rq*4+j, col0
    float h1_[4] = {0.f, 0.f, 0.f, 0.f};   // same, col1
    float zs0[4], zs1[4];

    // ---- init: zero sH, zero out[:,0,:], stage x[t=0] ----
    { half8 zz = {}; *(half8*)(sH + tid * 16) = zz; }
    for (int i = tid; i < 16 * 256; i += 512) {
        int r = i >> 8, c = i & 255;
        out[((size_t)(b0 + r) * 512) * 256 + c] = 0.f;
    }
    {
        size_t xo = (size_t)(b0 + wave) * 32768 + lane;   // x[b0+wave][0][lane]
        float a0 = x[xo], a1 = x[xo + (size_t)8 * 32768];
        *(f16*)(sX[0] + wave * 128       + ((lane * 2) ^ ((wave & 7) << 4))) = (f16)a0;
        *(f16*)(sX[0] + (wave + 8) * 128 + ((lane * 2) ^ ((wave & 7) << 4))) = (f16)a1;
    }
    __syncthreads();

    for (int t = 0; t < 511; ++t) {
        const int xb = t & 1;

        // prefetch x[t+1] (global), written to other LDS buffer mid-phase-A
        float xp0 = 0.f, xp1 = 0.f;
        if (t < 510) {
            size_t xo = (size_t)(b0 + wave) * 32768 + (size_t)(t + 1) * 64 + lane;
            xp0 = x[xo];
            xp1 = x[xo + (size_t)8 * 32768];
        }

        // ---- phase A: r,z pre-activations ----
        floatx4 aR0 = {0,0,0,0}, aR1 = {0,0,0,0}, aZ0 = {0,0,0,0}, aZ1 = {0,0,0,0};
        half8 xa0, xa1;
#pragma unroll
        for (int kt = 0; kt < 8; ++kt) {
            half8 av = *(const half8*)(sH + abase + ((kt * 64 + rq * 16) ^ asw));
            aR0 = MFMA16(av, pR0[kt * 64], aR0);
            aR1 = MFMA16(av, pR1[kt * 64], aR1);
            aZ0 = MFMA16(av, pZ0[kt * 64], aZ0);
            aZ1 = MFMA16(av, pZ1[kt * 64], aZ1);
        }
        xa0 = *(const half8*)(sX[xb] + cl * 128 + ((rq * 16) ^ asw));
        xa1 = *(const half8*)(sX[xb] + cl * 128 + ((64 + rq * 16) ^ asw));
        aR0 = MFMA16(xa0, pR0[8 * 64], aR0);  aR1 = MFMA16(xa0, pR1[8 * 64], aR1);
        aZ0 = MFMA16(xa0, pZ0[8 * 64], aZ0);  aZ1 = MFMA16(xa0, pZ1[8 * 64], aZ1);
        aR0 = MFMA16(xa1, pR0[9 * 64], aR0);  aR1 = MFMA16(xa1, pR1[9 * 64], aR1);
        aZ0 = MFMA16(xa1, pZ0[9 * 64], aZ0);  aZ1 = MFMA16(xa1, pZ1[9 * 64], aZ1);

        // stage x[t+1] into the other buffer (readers separated by loop-end barrier)
        if (t < 510) {
            const int nb = xb ^ 1;
            *(f16*)(sX[nb] + wave * 128       + ((lane * 2) ^ ((wave & 7) << 4))) = (f16)xp0;
            *(f16*)(sX[nb] + (wave + 8) * 128 + ((lane * 2) ^ ((wave & 7) << 4))) = (f16)xp1;
        }

        // epilogue A: r,z; write r*h to sRH
#pragma unroll
        for (int j = 0; j < 4; ++j) {
            const int row = rq * 4 + j;
            float r0 = 1.f / (1.f + __expf(-(aR0[j] + bR0)));
            float r1 = 1.f / (1.f + __expf(-(aR1[j] + bR1)));
            zs0[j]   = 1.f / (1.f + __expf(-(aZ0[j] + bZ0)));
            zs1[j]   = 1.f / (1.f + __expf(-(aZ1[j] + bZ1)));
            const int sw = (row & 7) << 4;
            *(f16*)(sRH + row * 512 + ((col0 * 2) ^ sw)) = (f16)(r0 * h0_[j]);
            *(f16*)(sRH + row * 512 + ((col1 * 2) ^ sw)) = (f16)(r1 * h1_[j]);
        }
        __syncthreads();

        // ---- phase B: g pre-activation from (r*h) and x ----
        floatx4 aG0 = {0,0,0,0}, aG1 = {0,0,0,0};
#pragma unroll
        for (int kt = 0; kt < 8; ++kt) {
            half8 av = *(const half8*)(sRH + abase + ((kt * 64 + rq * 16) ^ asw));
            aG0 = MFMA16(av, pG0[kt * 64], aG0);
            aG1 = MFMA16(av, pG1[kt * 64], aG1);
        }
        aG0 = MFMA16(xa0, pG0[8 * 64], aG0);  aG1 = MFMA16(xa0, pG1[8 * 64], aG1);
        aG0 = MFMA16(xa1, pG0[9 * 64], aG0);  aG1 = MFMA16(xa1, pG1[9 * 64], aG1);

        // epilogue B: g = tanh, blend h_new, write out + sH
#pragma unroll
        for (int j = 0; j < 4; ++j) {
            const int row = rq * 4 + j;
            float e0 = __expf(2.f * (aG0[j] + bG0));
            float g0 = 1.f - 2.f / (e0 + 1.f);          // tanh, inf-safe
            float e1 = __expf(2.f * (aG1[j] + bG1));
            float g1 = 1.f - 2.f / (e1 + 1.f);
            float hn0 = h0_[j] + zs0[j] * (g0 - h0_[j]); // (1-z)h + z g
            float hn1 = h1_[j] + zs1[j] * (g1 - h1_[j]);
            h0_[j] = hn0;
            h1_[j] = hn1;
            const int sw = (row & 7) << 4;
            *(f16*)(sH + row * 512 + ((col0 * 2) ^ sw)) = (f16)hn0;
            *(f16*)(sH + row * 512 + ((col1 * 2) ^ sw)) = (f16)hn1;
            size_t ob = ((size_t)(b0 + row) * 512 + (t + 1)) * 256;
            out[ob + col0] = hn0;
            out[ob + col1] = hn1;
        }
        __syncthreads();
    }
}

extern "C" void kernel_launch(void* const* d_in, const int* in_sizes, int n_in,
                              void* d_out, int out_size, void* d_ws, size_t ws_size,
                              hipStream_t stream) {
    const float* x  = (const float*)d_in[0];
    const float* Wr = (const float*)d_in[1];
    const float* br = (const float*)d_in[2];
    const float* Wz = (const float*)d_in[3];
    const float* bz = (const float*)d_in[4];
    const float* Wg = (const float*)d_in[5];
    const float* bg = (const float*)d_in[6];
    const float* Hr = (const float*)d_in[7];
    const float* Hz = (const float*)d_in[8];
    const float* Hg = (const float*)d_in[9];

    f16* Bfrag = (f16*)d_ws;   // 3*16*10*64*8 f16 = 491,520 B

    gru_prep<<<120, 256, 0, stream>>>(Wr, Wz, Wg, Hr, Hz, Hg, Bfrag);
    gru_scan<<<16, 512, 0, stream>>>(x, br, bz, bg, Bfrag, (float*)d_out);
}

// Round 2
// 2125.122 us; speedup vs baseline: 1.5192x; 1.5192x over previous
//
#include <hip/hip_runtime.h>
#include <hip/hip_bf16.h>

// GRU forward v2 — CU-resident weights.
//   Round-1 lesson: streaming the 480KB weight-fragment table from L2 every
//   step is the bottleneck (~3.4us/step of per-CU L2 BW). v2 keeps Hr,Hz in
//   VGPRs (256/thread), Hg kt0..5 in LDS (96KB), Hg kt6,7 in VGPRs, and
//   precomputes the x-projections (x@W+b) into d_ws as f16 D-fragments so the
//   scan kernel touches no weight memory beyond its own CU.
//   Scan: 16 WGs x 256 threads (4 waves, 1 wave/SIMD, 512-VGPR budget).
//   Raw s_barrier + lgkmcnt(0) (no vmcnt drain) keeps out-stores/prefetch
//   loads in flight across steps.

typedef _Float16 f16;
typedef _Float16 half8 __attribute__((ext_vector_type(8)));
typedef float floatx4 __attribute__((ext_vector_type(4)));

#define MFMA16(a, b, c) __builtin_amdgcn_mfma_f32_16x16x32_f16((a), (b), (c), 0, 0, 0)

// ---- workspace layout (bytes) ----
#define WTAB_OFF   0u          // W frags  [g3][nt16][ktx2][lane64][16B] = 98304
#define RZTAB_OFF  98304u      // RZ frags [tid256][g2][nti4][kt8][16B] = 262144
#define GLDS_OFF   360448u     // G frags  [nt16][kt6][lane64][16B]     = 98304
#define GREG_OFF   458752u     // G frags  [tid256][nti4][ktx2][16B]    = 32768
#define PRE_OFF    491520u     // pre-gates [bid 511*16][i6][tid256][16B] = 200933376
#define WS_NEED    (491520ull + 200933376ull)

// =====================================================================
// v2 prep: all weight-fragment tables
// =====================================================================
__global__ void gru_wprep(const float* __restrict__ Wr, const float* __restrict__ Wz,
                          const float* __restrict__ Wg, const float* __restrict__ Hr,
                          const float* __restrict__ Hz, const float* __restrict__ Hg,
                          f16* __restrict__ ws) {
    int idx = blockIdx.x * 256 + threadIdx.x;   // 0..30719
    if (idx >= 30720) return;
    const float* src;
    int col, k0;
    f16* dst;
    if (idx < 6144) {                            // Wtab: ((g*16+nt)*2+ktx)*64+lane
        int lane = idx & 63, ktx = (idx >> 6) & 1, nt = (idx >> 7) & 15, g = idx >> 11;
        src = (g == 0) ? Wr : (g == 1) ? Wz : Wg;
        col = nt * 16 + (lane & 15);
        k0  = ktx * 32 + (lane >> 4) * 8;
        dst = ws + WTAB_OFF / 2 + (size_t)idx * 8;
    } else if (idx < 22528) {                    // RZtab: tid*64 + g*32 + nti*8 + kt
        int local = idx - 6144;
        int kt = local & 7, nti = (local >> 3) & 3, g = (local >> 5) & 1, tid = local >> 6;
        int w = tid >> 6, l = tid & 63;
        src = g ? Hz : Hr;
        col = (w * 4 + nti) * 16 + (l & 15);
        k0  = kt * 32 + (l >> 4) * 8;
        dst = ws + RZTAB_OFF / 2 + (size_t)local * 8;
    } else if (idx < 28672) {                    // Gldstab: (nt*6+kt)*64+lane
        int local = idx - 22528;
        int lane = local & 63, q = local >> 6;
        int kt = q % 6, nt = q / 6;
        src = Hg;
        col = nt * 16 + (lane & 15);
        k0  = kt * 32 + (lane >> 4) * 8;
        dst = ws + GLDS_OFF / 2 + (size_t)local * 8;
    } else {                                     // Gregtab: tid*8 + nti*2 + ktx
        int local = idx - 28672;
        int ktx = local & 1, nti = (local >> 1) & 3, tid = local >> 3;
        int w = tid >> 6, l = tid & 63;
        src = Hg;
        col = (w * 4 + nti) * 16 + (l & 15);
        k0  = (6 + ktx) * 32 + (l >> 4) * 8;
        dst = ws + GREG_OFF / 2 + (size_t)local * 8;
    }
    half8 v;
#pragma unroll
    for (int i = 0; i < 8; ++i) v[i] = (f16)src[(size_t)(k0 + i) * 256 + col];
    *(half8*)dst = v;
}

// =====================================================================
// v2 prep: pre-gates  pre[t][blk] = x[blk rows, t] @ [Wr|Wz|Wg] + b  (f16 D-frags)
// =====================================================================
__global__ void __launch_bounds__(256)
gru_gates(const float* __restrict__ x, const float* __restrict__ br,
          const float* __restrict__ bz, const float* __restrict__ bg,
          f16* __restrict__ ws) {
    const int bid = blockIdx.x;                  // t*16 + blk, t in [0,511)
    const int t = bid >> 4, blk = bid & 15;
    const int tid = threadIdx.x, w = tid >> 6, l = tid & 63;
    const int cl = l & 15, rq = l >> 4;

    // A-fragments from x (row = batch row, k = feature)
    half8 xa[2];
    const float* xr = x + (size_t)(blk * 16 + cl) * 32768 + (size_t)t * 64 + rq * 8;
#pragma unroll
    for (int ktx = 0; ktx < 2; ++ktx) {
        float4 a = *(const float4*)(xr + ktx * 32);
        float4 b = *(const float4*)(xr + ktx * 32 + 4);
        half8 v;
        v[0] = (f16)a.x; v[1] = (f16)a.y; v[2] = (f16)a.z; v[3] = (f16)a.w;
        v[4] = (f16)b.x; v[5] = (f16)b.y; v[6] = (f16)b.z; v[7] = (f16)b.w;
        xa[ktx] = v;
    }

    const half8* Wt = (const half8*)(ws + WTAB_OFF / 2);
    floatx4 acc[3][4];
#pragma unroll
    for (int g = 0; g < 3; ++g)
#pragma unroll
        for (int nti = 0; nti < 4; ++nti) {
            int col = (w * 4 + nti) * 16 + cl;
            float b = (g == 0 ? br : g == 1 ? bz : bg)[col];
            acc[g][nti] = (floatx4){b, b, b, b};
        }
#pragma unroll
    for (int g = 0; g < 3; ++g)
#pragma unroll
        for (int nti = 0; nti < 4; ++nti) {
            int nt = w * 4 + nti;
#pragma unroll
            for (int ktx = 0; ktx < 2; ++ktx)
                acc[g][nti] = MFMA16(xa[ktx], Wt[(size_t)(((g * 16 + nt) * 2 + ktx)) * 64 + l],
                                     acc[g][nti]);
        }

    // store: pre[bid][i][tid] half8, element q=i*8+e maps to (g,nti,j)=(q>>4,(q>>2)&3,q&3)
    half8* preb = (half8*)(ws + PRE_OFF / 2);
#pragma unroll
    for (int i = 0; i < 6; ++i) {
        half8 v;
#pragma unroll
        for (int e = 0; e < 8; ++e) {
            int q = i * 8 + e;
            v[e] = (f16)acc[q >> 4][(q >> 2) & 3][q & 3];
        }
        preb[((size_t)bid * 6 + i) * 256 + tid] = v;
    }
}

// =====================================================================
// v2 scan: 16 WGs x 256 threads, weights CU-resident
// =====================================================================
__global__ void __launch_bounds__(256, 1)
gru_scan2(const f16* __restrict__ ws, float* __restrict__ out) {
    extern __shared__ unsigned char smem[];
    unsigned char* sH  = smem;               // 8192  : h  f16 [16][256] swizzled
    unsigned char* sRH = smem + 8192;        // 8192  : r*h f16 [16][256] swizzled
    unsigned char* sG  = smem + 16384;       // 98304 : Hg frags [nt16][kt6][lane64][16B]

    const int tid = threadIdx.x, w = tid >> 6, l = tid & 63;
    const int cl = l & 15, rq = l >> 4;
    const int blk = blockIdx.x, b0 = blk * 16;

    // ---- load register-resident weights ----
    half8 rz[2][4][8];
    {
        const half8* rzt = (const half8*)(ws + RZTAB_OFF / 2) + (size_t)tid * 64;
#pragma unroll
        for (int g = 0; g < 2; ++g)
#pragma unroll
            for (int nti = 0; nti < 4; ++nti)
#pragma unroll
                for (int kt = 0; kt < 8; ++kt)
                    rz[g][nti][kt] = rzt[g * 32 + nti * 8 + kt];
    }
    half8 gr[4][2];
    {
        const half8* grt = (const half8*)(ws + GREG_OFF / 2) + (size_t)tid * 8;
#pragma unroll
        for (int nti = 0; nti < 4; ++nti)
#pragma unroll
            for (int ktx = 0; ktx < 2; ++ktx)
                gr[nti][ktx] = grt[nti * 2 + ktx];
    }
    // ---- stage Hg kt0..5 into LDS (96KB) ----
    {
        const uint4* src = (const uint4*)(ws + GLDS_OFF / 2);
        uint4* dst = (uint4*)sG;
#pragma unroll
        for (int i = 0; i < 24; ++i) dst[tid + i * 256] = src[tid + i * 256];
    }
    // ---- zero sH, out[:,0,:] ----
    {
        uint4 z = {};
        ((uint4*)sH)[tid] = z;
        ((uint4*)sH)[256 + tid] = z;
    }
    for (int i = tid; i < 4096; i += 256) {
        int row = i >> 8, col = i & 255;
        out[(size_t)(b0 + row) * 131072 + col] = 0.f;
    }

    float h[4][4] = {};
    float zs[4][4];

    // ---- preload gates for t=0 ----
    const half8* preb = (const half8*)(ws + PRE_OFF / 2);
    half8 ucur[6], unxt[6] = {};
#pragma unroll
    for (int i = 0; i < 6; ++i)
        ucur[i] = preb[((size_t)(blk)*6 + i) * 256 + tid];

    asm volatile("s_waitcnt lgkmcnt(0)" ::: "memory");
    __builtin_amdgcn_s_barrier();
    __builtin_amdgcn_sched_barrier(0);

    const int abase = cl * 512;
    const int asw   = (cl & 7) << 4;

    for (int t = 0; t < 511; ++t) {
        // prefetch next step's gates (consumed next iteration; compiler vmcnt-tracks)
        if (t < 510) {
            const half8* p = preb + ((size_t)((t + 1) * 16 + blk) * 6) * 256 + tid;
#pragma unroll
            for (int i = 0; i < 6; ++i) unxt[i] = p[i * 256];
        }

        // ---- phase A: R,Z pre-activations (K=256 from sH, B-frags in regs) ----
        floatx4 aR[4] = {}, aZ[4] = {};
#pragma unroll
        for (int kt = 0; kt < 8; ++kt) {
            half8 av = *(const half8*)(sH + abase + ((kt * 64 + rq * 16) ^ asw));
#pragma unroll
            for (int nti = 0; nti < 4; ++nti) {
                aR[nti] = MFMA16(av, rz[0][nti][kt], aR[nti]);
                aZ[nti] = MFMA16(av, rz[1][nti][kt], aZ[nti]);
            }
        }

        // ---- epilogue A: r,z; write r*h (f16) to sRH ----
#pragma unroll
        for (int nti = 0; nti < 4; ++nti) {
            int col = (w * 4 + nti) * 16 + cl;
#pragma unroll
            for (int j = 0; j < 4; ++j) {
                int row = rq * 4 + j;
                int qr = nti * 4 + j, qz = 16 + nti * 4 + j;
                float r = 1.f / (1.f + __expf(-(aR[nti][j] + (float)ucur[qr >> 3][qr & 7])));
                float z = 1.f / (1.f + __expf(-(aZ[nti][j] + (float)ucur[qz >> 3][qz & 7])));
                zs[nti][j] = z;
                *(f16*)(sRH + row * 512 + ((col * 2) ^ ((row & 7) << 4))) = (f16)(r * h[nti][j]);
            }
        }
        asm volatile("s_waitcnt lgkmcnt(0)" ::: "memory");
        __builtin_amdgcn_s_barrier();
        __builtin_amdgcn_sched_barrier(0);

        // ---- phase B: G pre-activation (K=256 from sRH; B-frags LDS kt0..5, regs kt6..7) ----
        floatx4 aG[4] = {};
#pragma unroll
        for (int kt = 0; kt < 6; ++kt) {
            half8 av = *(const half8*)(sRH + abase + ((kt * 64 + rq * 16) ^ asw));
#pragma unroll
            for (int nti = 0; nti < 4; ++nti) {
                half8 bf = *(const half8*)(sG + (size_t)((((w * 4 + nti) * 6 + kt) * 64 + l)) * 16);
                aG[nti] = MFMA16(av, bf, aG[nti]);
            }
        }
#pragma unroll
        for (int ktx = 0; ktx < 2; ++ktx) {
            int kt = 6 + ktx;
            half8 av = *(const half8*)(sRH + abase + ((kt * 64 + rq * 16) ^ asw));
#pragma unroll
            for (int nti = 0; nti < 4; ++nti)
                aG[nti] = MFMA16(av, gr[nti][ktx], aG[nti]);
        }

        // ---- epilogue B: g=tanh, blend, write h to sH + out ----
#pragma unroll
        for (int nti = 0; nti < 4; ++nti) {
            int col = (w * 4 + nti) * 16 + cl;
#pragma unroll
            for (int j = 0; j < 4; ++j) {
                int row = rq * 4 + j;
                int qg = 32 + nti * 4 + j;
                float e = __expf(2.f * (aG[nti][j] + (float)ucur[qg >> 3][qg & 7]));
                float g = 1.f - 2.f / (e + 1.f);          // tanh, inf-safe
                float hn = h[nti][j] + zs[nti][j] * (g - h[nti][j]);
                h[nti][j] = hn;
                *(f16*)(sH + row * 512 + ((col * 2) ^ ((row & 7) << 4))) = (f16)hn;
                out[(size_t)(b0 + row) * 131072 + (size_t)(t + 1) * 256 + col] = hn;
            }
        }
#pragma unroll
        for (int i = 0; i < 6; ++i) ucur[i] = unxt[i];
        asm volatile("s_waitcnt lgkmcnt(0)" ::: "memory");
        __builtin_amdgcn_s_barrier();
        __builtin_amdgcn_sched_barrier(0);
    }
}

// =====================================================================
// v1 fallback (round-1 kernels, proven correct) — used if ws too small
// =====================================================================
__global__ void gru_prep(const float* __restrict__ Wr, const float* __restrict__ Wz,
                         const float* __restrict__ Wg, const float* __restrict__ Hr,
                         const float* __restrict__ Hz, const float* __restrict__ Hg,
                         f16* __restrict__ B) {
    int idx = blockIdx.x * 256 + threadIdx.x;
    int lane = idx & 63;
    int rest = idx >> 6;
    int kt = rest % 10;
    rest /= 10;
    int nt = rest & 15;
    int g  = rest >> 4;
    if (g >= 3) return;
    const float* H = (g == 0) ? Hr : (g == 1) ? Hz : Hg;
    const float* W = (g == 0) ? Wr : (g == 1) ? Wz : Wg;
    int col   = nt * 16 + (lane & 15);
    int kbase = kt * 32 + (lane >> 4) * 8;
    half8 v;
#pragma unroll
    for (int i = 0; i < 8; ++i) {
        int k = kbase + i;
        float val = (k < 256) ? H[k * 256 + col] : W[(k - 256) * 256 + col];
        v[i] = (f16)val;
    }
    *(half8*)(B + (size_t)idx * 8) = v;
}

__global__ void __launch_bounds__(512, 1)
gru_scan(const float* __restrict__ x,
         const float* __restrict__ br, const float* __restrict__ bz,
         const float* __restrict__ bg,
         const f16* __restrict__ Bfrag,
         float* __restrict__ out) {
    __shared__ __align__(16) unsigned char sH[8192];
    __shared__ __align__(16) unsigned char sRH[8192];
    __shared__ __align__(16) unsigned char sX[2][2048];

    const int tid  = threadIdx.x;
    const int wave = tid >> 6;
    const int lane = tid & 63;
    const int cl   = lane & 15;
    const int rq   = lane >> 4;
    const int b0   = blockIdx.x * 16;
    const int nt0  = wave * 2, nt1 = wave * 2 + 1;
    const int col0 = nt0 * 16 + cl, col1 = nt1 * 16 + cl;

    const int abase = cl * 512;
    const int asw   = (cl & 7) << 4;

    const float bR0 = br[col0], bR1 = br[col1];
    const float bZ0 = bz[col0], bZ1 = bz[col1];
    const float bG0 = bg[col0], bG1 = bg[col1];

    const half8* Bb  = (const half8*)Bfrag;
    const half8* pR0 = Bb + (size_t)((0 * 16 + nt0) * 10) * 64 + lane;
    const half8* pR1 = Bb + (size_t)((0 * 16 + nt1) * 10) * 64 + lane;
    const half8* pZ0 = Bb + (size_t)((1 * 16 + nt0) * 10) * 64 + lane;
    const half8* pZ1 = Bb + (size_t)((1 * 16 + nt1) * 10) * 64 + lane;
    const half8* pG0 = Bb + (size_t)((2 * 16 + nt0) * 10) * 64 + lane;
    const half8* pG1 = Bb + (size_t)((2 * 16 + nt1) * 10) * 64 + lane;

    float h0_[4] = {0.f, 0.f, 0.f, 0.f};
    float h1_[4] = {0.f, 0.f, 0.f, 0.f};
    float zs0[4], zs1[4];

    { half8 zz = {}; *(half8*)(sH + tid * 16) = zz; }
    for (int i = tid; i < 16 * 256; i += 512) {
        int r = i >> 8, c = i & 255;
        out[((size_t)(b0 + r) * 512) * 256 + c] = 0.f;
    }
    {
        size_t xo = (size_t)(b0 + wave) * 32768 + lane;
        float a0 = x[xo], a1 = x[xo + (size_t)8 * 32768];
        *(f16*)(sX[0] + wave * 128       + ((lane * 2) ^ ((wave & 7) << 4))) = (f16)a0;
        *(f16*)(sX[0] + (wave + 8) * 128 + ((lane * 2) ^ ((wave & 7) << 4))) = (f16)a1;
    }
    __syncthreads();

    for (int t = 0; t < 511; ++t) {
        const int xb = t & 1;
        float xp0 = 0.f, xp1 = 0.f;
        if (t < 510) {
            size_t xo = (size_t)(b0 + wave) * 32768 + (size_t)(t + 1) * 64 + lane;
            xp0 = x[xo];
            xp1 = x[xo + (size_t)8 * 32768];
        }

        floatx4 aR0 = {0,0,0,0}, aR1 = {0,0,0,0}, aZ0 = {0,0,0,0}, aZ1 = {0,0,0,0};
        half8 xa0, xa1;
#pragma unroll
        for (int kt = 0; kt < 8; ++kt) {
            half8 av = *(const half8*)(sH + abase + ((kt * 64 + rq * 16) ^ asw));
            aR0 = MFMA16(av, pR0[kt * 64], aR0);
            aR1 = MFMA16(av, pR1[kt * 64], aR1);
            aZ0 = MFMA16(av, pZ0[kt * 64], aZ0);
            aZ1 = MFMA16(av, pZ1[kt * 64], aZ1);
        }
        xa0 = *(const half8*)(sX[xb] + cl * 128 + ((rq * 16) ^ asw));
        xa1 = *(const half8*)(sX[xb] + cl * 128 + ((64 + rq * 16) ^ asw));
        aR0 = MFMA16(xa0, pR0[8 * 64], aR0);  aR1 = MFMA16(xa0, pR1[8 * 64], aR1);
        aZ0 = MFMA16(xa0, pZ0[8 * 64], aZ0);  aZ1 = MFMA16(xa0, pZ1[8 * 64], aZ1);
        aR0 = MFMA16(xa1, pR0[9 * 64], aR0);  aR1 = MFMA16(xa1, pR1[9 * 64], aR1);
        aZ0 = MFMA16(xa1, pZ0[9 * 64], aZ0);  aZ1 = MFMA16(xa1, pZ1[9 * 64], aZ1);

        if (t < 510) {
            const int nb = xb ^ 1;
            *(f16*)(sX[nb] + wave * 128       + ((lane * 2) ^ ((wave & 7) << 4))) = (f16)xp0;
            *(f16*)(sX[nb] + (wave + 8) * 128 + ((lane * 2) ^ ((wave & 7) << 4))) = (f16)xp1;
        }

#pragma unroll
        for (int j = 0; j < 4; ++j) {
            const int row = rq * 4 + j;
            float r0 = 1.f / (1.f + __expf(-(aR0[j] + bR0)));
            float r1 = 1.f / (1.f + __expf(-(aR1[j] + bR1)));
            zs0[j]   = 1.f / (1.f + __expf(-(aZ0[j] + bZ0)));
            zs1[j]   = 1.f / (1.f + __expf(-(aZ1[j] + bZ1)));
            const int sw = (row & 7) << 4;
            *(f16*)(sRH + row * 512 + ((col0 * 2) ^ sw)) = (f16)(r0 * h0_[j]);
            *(f16*)(sRH + row * 512 + ((col1 * 2) ^ sw)) = (f16)(r1 * h1_[j]);
        }
        __syncthreads();

        floatx4 aG0 = {0,0,0,0}, aG1 = {0,0,0,0};
#pragma unroll
        for (int kt = 0; kt < 8; ++kt) {
            half8 av = *(const half8*)(sRH + abase + ((kt * 64 + rq * 16) ^ asw));
            aG0 = MFMA16(av, pG0[kt * 64], aG0);
            aG1 = MFMA16(av, pG1[kt * 64], aG1);
        }
        aG0 = MFMA16(xa0, pG0[8 * 64], aG0);  aG1 = MFMA16(xa0, pG1[8 * 64], aG1);
        aG0 = MFMA16(xa1, pG0[9 * 64], aG0);  aG1 = MFMA16(xa1, pG1[9 * 64], aG1);

#pragma unroll
        for (int j = 0; j < 4; ++j) {
            const int row = rq * 4 + j;
            float e0 = __expf(2.f * (aG0[j] + bG0));
            float g0 = 1.f - 2.f / (e0 + 1.f);
            float e1 = __expf(2.f * (aG1[j] + bG1));
            float g1 = 1.f - 2.f / (e1 + 1.f);
            float hn0 = h0_[j] + zs0[j] * (g0 - h0_[j]);
            float hn1 = h1_[j] + zs1[j] * (g1 - h1_[j]);
            h0_[j] = hn0;
            h1_[j] = hn1;
            const int sw = (row & 7) << 4;
            *(f16*)(sH + row * 512 + ((col0 * 2) ^ sw)) = (f16)hn0;
            *(f16*)(sH + row * 512 + ((col1 * 2) ^ sw)) = (f16)hn1;
            size_t ob = ((size_t)(b0 + row) * 512 + (t + 1)) * 256;
            out[ob + col0] = hn0;
            out[ob + col1] = hn1;
        }
        __syncthreads();
    }
}

extern "C" void kernel_launch(void* const* d_in, const int* in_sizes, int n_in,
                              void* d_out, int out_size, void* d_ws, size_t ws_size,
                              hipStream_t stream) {
    const float* x  = (const float*)d_in[0];
    const float* Wr = (const float*)d_in[1];
    const float* br = (const float*)d_in[2];
    const float* Wz = (const float*)d_in[3];
    const float* bz = (const float*)d_in[4];
    const float* Wg = (const float*)d_in[5];
    const float* bg = (const float*)d_in[6];
    const float* Hr = (const float*)d_in[7];
    const float* Hz = (const float*)d_in[8];
    const float* Hg = (const float*)d_in[9];
    float* out = (float*)d_out;

    if (ws_size >= WS_NEED) {
        f16* ws = (f16*)d_ws;
        gru_wprep<<<120, 256, 0, stream>>>(Wr, Wz, Wg, Hr, Hz, Hg, ws);
        gru_gates<<<511 * 16, 256, 0, stream>>>(x, br, bz, bg, ws);
        (void)hipFuncSetAttribute((const void*)gru_scan2,
                                  hipFuncAttributeMaxDynamicSharedMemorySize, 114688);
        gru_scan2<<<16, 256, 114688, stream>>>(ws, out);
    } else {
        f16* Bfrag = (f16*)d_ws;
        gru_prep<<<120, 256, 0, stream>>>(Wr, Wz, Wg, Hr, Hz, Hg, Bfrag);
        gru_scan<<<16, 512, 0, stream>>>(x, br, bz, bg, Bfrag, out);
    }
}

// Round 3
// 1075.410 us; speedup vs baseline: 3.0020x; 1.9761x over previous
//
#include <hip/hip_runtime.h>
#include <hip/hip_bf16.h>

// GRU forward v3 — actually-CU-resident weights.
//   Round-2 lesson: at 256 threads the per-thread weight footprint (288+ VGPRs)
//   exceeded the register file; the compiler rematerialized the weight loads
//   inside the scan loop -> still L2-streaming ~256KB/step (4us/step).
//   v3: 512 threads (8 waves, 2/SIMD). Each wave owns 2 N-tiles:
//     - Hr,Hz fragments in VGPRs: 32 half8 = 128 VGPRs/thread (asm-pinned).
//     - Hg fragments entirely in LDS: 128KB.
//     - x-projections precomputed to d_ws (f16 D-frags), streamed + dbuf.
//   2 waves/SIMD gives TLP; epilogue work per thread halves; sigmoid/tanh
//   use v_rcp_f32 to avoid refinement chains.

typedef _Float16 f16;
typedef _Float16 half8 __attribute__((ext_vector_type(8)));
typedef float floatx4 __attribute__((ext_vector_type(4)));

#define MFMA16(a, b, c) __builtin_amdgcn_mfma_f32_16x16x32_f16((a), (b), (c), 0, 0, 0)

// ---- workspace layout (bytes) ----
#define WTAB_OFF   0u          // W frags  [g3][nt16][ktx2][lane64][16B] = 98304
#define RZTAB_OFF  98304u      // RZ frags [tid512][g2][nti2][kt8][16B]  = 262144
#define GTAB_OFF   360448u     // Hg frags [nt16][kt8][lane64][16B]      = 131072
#define PRE_OFF    491520u     // pre-gates [bid 511*16][g3][tid512][16B] = 200933376
#define WS_NEED    (491520ull + 200933376ull)

// =====================================================================
// prep: weight-fragment tables (30720 half8 total)
// =====================================================================
__global__ void gru_wprep(const float* __restrict__ Wr, const float* __restrict__ Wz,
                          const float* __restrict__ Wg, const float* __restrict__ Hr,
                          const float* __restrict__ Hz, const float* __restrict__ Hg,
                          f16* __restrict__ ws) {
    int idx = blockIdx.x * 256 + threadIdx.x;   // 0..30719
    if (idx >= 30720) return;
    const float* src;
    int col, k0;
    f16* dst;
    if (idx < 6144) {                            // Wtab: ((g*16+nt)*2+ktx)*64+lane
        int lane = idx & 63, ktx = (idx >> 6) & 1, nt = (idx >> 7) & 15, g = idx >> 11;
        src = (g == 0) ? Wr : (g == 1) ? Wz : Wg;
        col = nt * 16 + (lane & 15);
        k0  = ktx * 32 + (lane >> 4) * 8;
        dst = ws + WTAB_OFF / 2 + (size_t)idx * 8;
    } else if (idx < 22528) {                    // RZtab: tid*32 + g*16 + nti*8 + kt
        int local = idx - 6144;
        int kt = local & 7, nti = (local >> 3) & 1, g = (local >> 4) & 1, tid = local >> 5;
        int w = tid >> 6, l = tid & 63;
        src = g ? Hz : Hr;
        col = (w * 2 + nti) * 16 + (l & 15);
        k0  = kt * 32 + (l >> 4) * 8;
        dst = ws + RZTAB_OFF / 2 + (size_t)local * 8;
    } else {                                     // Gtab: (nt*8+kt)*64+lane
        int local = idx - 22528;                 // 0..8191
        int lane = local & 63, q = local >> 6;
        int kt = q & 7, nt = q >> 3;
        src = Hg;
        col = nt * 16 + (lane & 15);
        k0  = kt * 32 + (lane >> 4) * 8;
        dst = ws + GTAB_OFF / 2 + (size_t)local * 8;
    }
    half8 v;
#pragma unroll
    for (int i = 0; i < 8; ++i) v[i] = (f16)src[(size_t)(k0 + i) * 256 + col];
    *(half8*)dst = v;
}

// =====================================================================
// prep: pre-gates  pre[t][blk][g][tid] = (x_t @ W_g + b_g) D-fragment, f16
// =====================================================================
__global__ void __launch_bounds__(512)
gru_gates(const float* __restrict__ x, const float* __restrict__ br,
          const float* __restrict__ bz, const float* __restrict__ bg,
          f16* __restrict__ ws) {
    const int bid = blockIdx.x;                  // t*16 + blk, t in [0,511)
    const int t = bid >> 4, blk = bid & 15;
    const int tid = threadIdx.x, w = tid >> 6, l = tid & 63;
    const int cl = l & 15, rq = l >> 4;

    half8 xa[2];
    const float* xr = x + (size_t)(blk * 16 + cl) * 32768 + (size_t)t * 64 + rq * 8;
#pragma unroll
    for (int ktx = 0; ktx < 2; ++ktx) {
        float4 a = *(const float4*)(xr + ktx * 32);
        float4 b = *(const float4*)(xr + ktx * 32 + 4);
        half8 v;
        v[0] = (f16)a.x; v[1] = (f16)a.y; v[2] = (f16)a.z; v[3] = (f16)a.w;
        v[4] = (f16)b.x; v[5] = (f16)b.y; v[6] = (f16)b.z; v[7] = (f16)b.w;
        xa[ktx] = v;
    }

    const half8* Wt = (const half8*)(ws + WTAB_OFF / 2);
    floatx4 acc[3][2];
#pragma unroll
    for (int g = 0; g < 3; ++g)
#pragma unroll
        for (int nti = 0; nti < 2; ++nti) {
            int col = (w * 2 + nti) * 16 + cl;
            float b = (g == 0 ? br : g == 1 ? bz : bg)[col];
            acc[g][nti] = (floatx4){b, b, b, b};
        }
#pragma unroll
    for (int g = 0; g < 3; ++g)
#pragma unroll
        for (int nti = 0; nti < 2; ++nti) {
            int nt = w * 2 + nti;
#pragma unroll
            for (int ktx = 0; ktx < 2; ++ktx)
                acc[g][nti] = MFMA16(xa[ktx], Wt[(size_t)((g * 16 + nt) * 2 + ktx) * 64 + l],
                                     acc[g][nti]);
        }

    half8* preb = (half8*)(ws + PRE_OFF / 2);
#pragma unroll
    for (int g = 0; g < 3; ++g) {
        half8 v;
#pragma unroll
        for (int nti = 0; nti < 2; ++nti)
#pragma unroll
            for (int j = 0; j < 4; ++j)
                v[nti * 4 + j] = (f16)acc[g][nti][j];
        preb[((size_t)bid * 3 + g) * 512 + tid] = v;
    }
}

// =====================================================================
// scan: 16 WGs x 512 threads (8 waves, 2/SIMD)
// =====================================================================
__global__ void __launch_bounds__(512, 2)
gru_scan3(const f16* __restrict__ ws, float* __restrict__ out) {
    extern __shared__ unsigned char smem[];
    unsigned char* sH  = smem;               // 8192   : h   f16 [16][256] swizzled
    unsigned char* sRH = smem + 8192;        // 8192   : r*h f16 [16][256] swizzled
    unsigned char* sG  = smem + 16384;       // 131072 : Hg frags [nt16][kt8][lane64][16B]

    const int tid = threadIdx.x, w = tid >> 6, l = tid & 63;
    const int cl = l & 15, rq = l >> 4;
    const int blk = blockIdx.x, b0 = blk * 16;

    // ---- register-resident Hr,Hz fragments (128 VGPRs) ----
    half8 rz[2][2][8];
    {
        const half8* rzt = (const half8*)(ws + RZTAB_OFF / 2) + (size_t)tid * 32;
#pragma unroll
        for (int g = 0; g < 2; ++g)
#pragma unroll
            for (int nti = 0; nti < 2; ++nti)
#pragma unroll
                for (int kt = 0; kt < 8; ++kt)
                    rz[g][nti][kt] = rzt[g * 16 + nti * 8 + kt];
    }
#pragma unroll
    for (int g = 0; g < 2; ++g)
#pragma unroll
        for (int nti = 0; nti < 2; ++nti)
#pragma unroll
            for (int kt = 0; kt < 8; ++kt)
                asm volatile("" : "+v"(rz[g][nti][kt]));   // pin: block remat

    // ---- stage Hg into LDS (128KB) ----
    {
        const uint4* src = (const uint4*)(ws + GTAB_OFF / 2);
        uint4* dst = (uint4*)sG;
#pragma unroll
        for (int i = 0; i < 16; ++i) dst[tid + i * 512] = src[tid + i * 512];
    }
    // ---- zero sH; zero out[:,0,:] ----
    { uint4 z = {}; ((uint4*)sH)[tid] = z; }
    for (int i = tid; i < 4096; i += 512) {
        int row = i >> 8, col = i & 255;
        out[(size_t)(b0 + row) * 131072 + col] = 0.f;
    }

    float h[2][4] = {};
    float zs[2][4];

    const half8* preb = (const half8*)(ws + PRE_OFF / 2);
    half8 ucur[3], unxt[3] = {};
#pragma unroll
    for (int g = 0; g < 3; ++g)
        ucur[g] = preb[((size_t)blk * 3 + g) * 512 + tid];

    asm volatile("s_waitcnt lgkmcnt(0)" ::: "memory");
    __builtin_amdgcn_s_barrier();
    __builtin_amdgcn_sched_barrier(0);

    const int abase = cl * 512;
    const int asw   = (cl & 7) << 4;

    for (int t = 0; t < 511; ++t) {
        // prefetch next step's gates (consumed next iteration)
        if (t < 510) {
            const half8* p = preb + ((size_t)((t + 1) * 16 + blk) * 3) * 512 + tid;
#pragma unroll
            for (int g = 0; g < 3; ++g) unxt[g] = p[g * 512];
        }

        // ---- phase A: R,Z pre-activations (K=256 from sH, B-frags in regs) ----
        floatx4 aR[2] = {}, aZ[2] = {};
#pragma unroll
        for (int kt = 0; kt < 8; ++kt) {
            half8 av = *(const half8*)(sH + abase + ((kt * 64 + rq * 16) ^ asw));
#pragma unroll
            for (int nti = 0; nti < 2; ++nti) {
                aR[nti] = MFMA16(av, rz[0][nti][kt], aR[nti]);
                aZ[nti] = MFMA16(av, rz[1][nti][kt], aZ[nti]);
            }
        }

        // ---- epilogue A: r,z; write r*h (f16) to sRH ----
#pragma unroll
        for (int nti = 0; nti < 2; ++nti) {
            int col = (w * 2 + nti) * 16 + cl;
#pragma unroll
            for (int j = 0; j < 4; ++j) {
                int row = rq * 4 + j;
                int e = nti * 4 + j;
                float r = __builtin_amdgcn_rcpf(1.f + __expf(-(aR[nti][j] + (float)ucur[0][e])));
                float z = __builtin_amdgcn_rcpf(1.f + __expf(-(aZ[nti][j] + (float)ucur[1][e])));
                zs[nti][j] = z;
                *(f16*)(sRH + row * 512 + ((col * 2) ^ ((row & 7) << 4))) = (f16)(r * h[nti][j]);
            }
        }
        asm volatile("s_waitcnt lgkmcnt(0)" ::: "memory");
        __builtin_amdgcn_s_barrier();
        __builtin_amdgcn_sched_barrier(0);

        // ---- phase B: G pre-activation (A from sRH, B-frags from sG) ----
        floatx4 aG[2] = {};
#pragma unroll
        for (int kt = 0; kt < 8; ++kt) {
            half8 av = *(const half8*)(sRH + abase + ((kt * 64 + rq * 16) ^ asw));
#pragma unroll
            for (int nti = 0; nti < 2; ++nti) {
                int nt = w * 2 + nti;
                half8 bf = *(const half8*)(sG + (size_t)((nt * 8 + kt) * 64 + l) * 16);
                aG[nti] = MFMA16(av, bf, aG[nti]);
            }
        }

        // ---- epilogue B: g=tanh, blend, write h to sH + out ----
#pragma unroll
        for (int nti = 0; nti < 2; ++nti) {
            int col = (w * 2 + nti) * 16 + cl;
#pragma unroll
            for (int j = 0; j < 4; ++j) {
                int row = rq * 4 + j;
                int e = nti * 4 + j;
                float ex = __expf(2.f * (aG[nti][j] + (float)ucur[2][e]));
                float g = 1.f - 2.f * __builtin_amdgcn_rcpf(ex + 1.f);  // tanh, inf-safe
                float hn = h[nti][j] + zs[nti][j] * (g - h[nti][j]);
                h[nti][j] = hn;
                *(f16*)(sH + row * 512 + ((col * 2) ^ ((row & 7) << 4))) = (f16)hn;
                out[(size_t)(b0 + row) * 131072 + (size_t)(t + 1) * 256 + col] = hn;
            }
        }
#pragma unroll
        for (int g = 0; g < 3; ++g) ucur[g] = unxt[g];
        asm volatile("s_waitcnt lgkmcnt(0)" ::: "memory");
        __builtin_amdgcn_s_barrier();
        __builtin_amdgcn_sched_barrier(0);
    }
}

// =====================================================================
// v1 fallback (round-1 kernels, proven correct) — used if ws too small
// =====================================================================
__global__ void gru_prep(const float* __restrict__ Wr, const float* __restrict__ Wz,
                         const float* __restrict__ Wg, const float* __restrict__ Hr,
                         const float* __restrict__ Hz, const float* __restrict__ Hg,
                         f16* __restrict__ B) {
    int idx = blockIdx.x * 256 + threadIdx.x;
    int lane = idx & 63;
    int rest = idx >> 6;
    int kt = rest % 10;
    rest /= 10;
    int nt = rest & 15;
    int g  = rest >> 4;
    if (g >= 3) return;
    const float* H = (g == 0) ? Hr : (g == 1) ? Hz : Hg;
    const float* W = (g == 0) ? Wr : (g == 1) ? Wz : Wg;
    int col   = nt * 16 + (lane & 15);
    int kbase = kt * 32 + (lane >> 4) * 8;
    half8 v;
#pragma unroll
    for (int i = 0; i < 8; ++i) {
        int k = kbase + i;
        float val = (k < 256) ? H[k * 256 + col] : W[(k - 256) * 256 + col];
        v[i] = (f16)val;
    }
    *(half8*)(B + (size_t)idx * 8) = v;
}

__global__ void __launch_bounds__(512, 1)
gru_scan(const float* __restrict__ x,
         const float* __restrict__ br, const float* __restrict__ bz,
         const float* __restrict__ bg,
         const f16* __restrict__ Bfrag,
         float* __restrict__ out) {
    __shared__ __align__(16) unsigned char sH[8192];
    __shared__ __align__(16) unsigned char sRH[8192];
    __shared__ __align__(16) unsigned char sX[2][2048];

    const int tid  = threadIdx.x;
    const int wave = tid >> 6;
    const int lane = tid & 63;
    const int cl   = lane & 15;
    const int rq   = lane >> 4;
    const int b0   = blockIdx.x * 16;
    const int nt0  = wave * 2, nt1 = wave * 2 + 1;
    const int col0 = nt0 * 16 + cl, col1 = nt1 * 16 + cl;

    const int abase = cl * 512;
    const int asw   = (cl & 7) << 4;

    const float bR0 = br[col0], bR1 = br[col1];
    const float bZ0 = bz[col0], bZ1 = bz[col1];
    const float bG0 = bg[col0], bG1 = bg[col1];

    const half8* Bb  = (const half8*)Bfrag;
    const half8* pR0 = Bb + (size_t)((0 * 16 + nt0) * 10) * 64 + lane;
    const half8* pR1 = Bb + (size_t)((0 * 16 + nt1) * 10) * 64 + lane;
    const half8* pZ0 = Bb + (size_t)((1 * 16 + nt0) * 10) * 64 + lane;
    const half8* pZ1 = Bb + (size_t)((1 * 16 + nt1) * 10) * 64 + lane;
    const half8* pG0 = Bb + (size_t)((2 * 16 + nt0) * 10) * 64 + lane;
    const half8* pG1 = Bb + (size_t)((2 * 16 + nt1) * 10) * 64 + lane;

    float h0_[4] = {0.f, 0.f, 0.f, 0.f};
    float h1_[4] = {0.f, 0.f, 0.f, 0.f};
    float zs0[4], zs1[4];

    { half8 zz = {}; *(half8*)(sH + tid * 16) = zz; }
    for (int i = tid; i < 16 * 256; i += 512) {
        int r = i >> 8, c = i & 255;
        out[((size_t)(b0 + r) * 512) * 256 + c] = 0.f;
    }
    {
        size_t xo = (size_t)(b0 + wave) * 32768 + lane;
        float a0 = x[xo], a1 = x[xo + (size_t)8 * 32768];
        *(f16*)(sX[0] + wave * 128       + ((lane * 2) ^ ((wave & 7) << 4))) = (f16)a0;
        *(f16*)(sX[0] + (wave + 8) * 128 + ((lane * 2) ^ ((wave & 7) << 4))) = (f16)a1;
    }
    __syncthreads();

    for (int t = 0; t < 511; ++t) {
        const int xb = t & 1;
        float xp0 = 0.f, xp1 = 0.f;
        if (t < 510) {
            size_t xo = (size_t)(b0 + wave) * 32768 + (size_t)(t + 1) * 64 + lane;
            xp0 = x[xo];
            xp1 = x[xo + (size_t)8 * 32768];
        }

        floatx4 aR0 = {0,0,0,0}, aR1 = {0,0,0,0}, aZ0 = {0,0,0,0}, aZ1 = {0,0,0,0};
        half8 xa0, xa1;
#pragma unroll
        for (int kt = 0; kt < 8; ++kt) {
            half8 av = *(const half8*)(sH + abase + ((kt * 64 + rq * 16) ^ asw));
            aR0 = MFMA16(av, pR0[kt * 64], aR0);
            aR1 = MFMA16(av, pR1[kt * 64], aR1);
            aZ0 = MFMA16(av, pZ0[kt * 64], aZ0);
            aZ1 = MFMA16(av, pZ1[kt * 64], aZ1);
        }
        xa0 = *(const half8*)(sX[xb] + cl * 128 + ((rq * 16) ^ asw));
        xa1 = *(const half8*)(sX[xb] + cl * 128 + ((64 + rq * 16) ^ asw));
        aR0 = MFMA16(xa0, pR0[8 * 64], aR0);  aR1 = MFMA16(xa0, pR1[8 * 64], aR1);
        aZ0 = MFMA16(xa0, pZ0[8 * 64], aZ0);  aZ1 = MFMA16(xa0, pZ1[8 * 64], aZ1);
        aR0 = MFMA16(xa1, pR0[9 * 64], aR0);  aR1 = MFMA16(xa1, pR1[9 * 64], aR1);
        aZ0 = MFMA16(xa1, pZ0[9 * 64], aZ0);  aZ1 = MFMA16(xa1, pZ1[9 * 64], aZ1);

        if (t < 510) {
            const int nb = xb ^ 1;
            *(f16*)(sX[nb] + wave * 128       + ((lane * 2) ^ ((wave & 7) << 4))) = (f16)xp0;
            *(f16*)(sX[nb] + (wave + 8) * 128 + ((lane * 2) ^ ((wave & 7) << 4))) = (f16)xp1;
        }

#pragma unroll
        for (int j = 0; j < 4; ++j) {
            const int row = rq * 4 + j;
            float r0 = 1.f / (1.f + __expf(-(aR0[j] + bR0)));
            float r1 = 1.f / (1.f + __expf(-(aR1[j] + bR1)));
            zs0[j]   = 1.f / (1.f + __expf(-(aZ0[j] + bZ0)));
            zs1[j]   = 1.f / (1.f + __expf(-(aZ1[j] + bZ1)));
            const int sw = (row & 7) << 4;
            *(f16*)(sRH + row * 512 + ((col0 * 2) ^ sw)) = (f16)(r0 * h0_[j]);
            *(f16*)(sRH + row * 512 + ((col1 * 2) ^ sw)) = (f16)(r1 * h1_[j]);
        }
        __syncthreads();

        floatx4 aG0 = {0,0,0,0}, aG1 = {0,0,0,0};
#pragma unroll
        for (int kt = 0; kt < 8; ++kt) {
            half8 av = *(const half8*)(sRH + abase + ((kt * 64 + rq * 16) ^ asw));
            aG0 = MFMA16(av, pG0[kt * 64], aG0);
            aG1 = MFMA16(av, pG1[kt * 64], aG1);
        }
        aG0 = MFMA16(xa0, pG0[8 * 64], aG0);  aG1 = MFMA16(xa0, pG1[8 * 64], aG1);
        aG0 = MFMA16(xa1, pG0[9 * 64], aG0);  aG1 = MFMA16(xa1, pG1[9 * 64], aG1);

#pragma unroll
        for (int j = 0; j < 4; ++j) {
            const int row = rq * 4 + j;
            float e0 = __expf(2.f * (aG0[j] + bG0));
            float g0 = 1.f - 2.f / (e0 + 1.f);
            float e1 = __expf(2.f * (aG1[j] + bG1));
            float g1 = 1.f - 2.f / (e1 + 1.f);
            float hn0 = h0_[j] + zs0[j] * (g0 - h0_[j]);
            float hn1 = h1_[j] + zs1[j] * (g1 - h1_[j]);
            h0_[j] = hn0;
            h1_[j] = hn1;
            const int sw = (row & 7) << 4;
            *(f16*)(sH + row * 512 + ((col0 * 2) ^ sw)) = (f16)hn0;
            *(f16*)(sH + row * 512 + ((col1 * 2) ^ sw)) = (f16)hn1;
            size_t ob = ((size_t)(b0 + row) * 512 + (t + 1)) * 256;
            out[ob + col0] = hn0;
            out[ob + col1] = hn1;
        }
        __syncthreads();
    }
}

extern "C" void kernel_launch(void* const* d_in, const int* in_sizes, int n_in,
                              void* d_out, int out_size, void* d_ws, size_t ws_size,
                              hipStream_t stream) {
    const float* x  = (const float*)d_in[0];
    const float* Wr = (const float*)d_in[1];
    const float* br = (const float*)d_in[2];
    const float* Wz = (const float*)d_in[3];
    const float* bz = (const float*)d_in[4];
    const float* Wg = (const float*)d_in[5];
    const float* bg = (const float*)d_in[6];
    const float* Hr = (const float*)d_in[7];
    const float* Hz = (const float*)d_in[8];
    const float* Hg = (const float*)d_in[9];
    float* out = (float*)d_out;

    if (ws_size >= WS_NEED) {
        f16* ws = (f16*)d_ws;
        gru_wprep<<<120, 256, 0, stream>>>(Wr, Wz, Wg, Hr, Hz, Hg, ws);
        gru_gates<<<511 * 16, 512, 0, stream>>>(x, br, bz, bg, ws);
        (void)hipFuncSetAttribute((const void*)gru_scan3,
                                  hipFuncAttributeMaxDynamicSharedMemorySize, 147456);
        gru_scan3<<<16, 512, 147456, stream>>>(ws, out);
    } else {
        f16* Bfrag = (f16*)d_ws;
        gru_prep<<<120, 256, 0, stream>>>(Wr, Wz, Wg, Hr, Hz, Hg, Bfrag);
        gru_scan<<<16, 512, 0, stream>>>(x, br, bz, bg, Bfrag, out);
    }
}